// Round 9
// baseline (384.445 us; speedup 1.0000x reference)
//
#include <hip/hip_runtime.h>

// CrossAttention: B=4, L=256, D=2048, LE=2048, DE=1024, H=16, HD=128
// R9 = R8 + flash-attention fusion: S-GEMM + softmax + PV + combine_pv
//      replaced by one fused kernel (online softmax, P via LDS C->A layout
//      bounce, Vt as B^T). ctx written directly in [b*256+l][h*128+d] layout.

#define B_ 4
#define L_ 256
#define D_ 2048
#define LE_ 2048
#define DE_ 1024
#define H_ 16
#define HD_ 128

using f32x4  = __attribute__((ext_vector_type(4))) float;
using bf16x8 = __attribute__((ext_vector_type(8))) short;

__device__ __forceinline__ unsigned short f2bf(float f) {
    union { float f; unsigned int u; } v; v.f = f;
    unsigned int r = v.u + 0x7fffu + ((v.u >> 16) & 1u);   // RNE
    return (unsigned short)(r >> 16);
}
__device__ __forceinline__ float b2f(unsigned short h) {
    union { unsigned int u; float f; } v; v.u = ((unsigned int)h) << 16;
    return v.f;
}

__device__ __forceinline__ void load_lds16(const void* g, void* l) {
    __builtin_amdgcn_global_load_lds((const __attribute__((address_space(1))) void*)g,
                                     (__attribute__((address_space(3))) void*)l, 16, 0, 0);
}

// ---------------- fused cast fp32 -> bf16 for x and enc ----------------
__global__ void cast_all(const float* __restrict__ x, const float* __restrict__ enc,
                         unsigned short* __restrict__ x_bf, unsigned short* __restrict__ enc_bf) {
    long i = (long)(blockIdx.x * 256 + threadIdx.x) * 4;   // 10,485,760 elements total
    const float* in;
    unsigned short* out;
    if (i < 2097152) { in = x + i; out = x_bf + i; }
    else             { in = enc + (i - 2097152); out = enc_bf + (i - 2097152); }
    float4 v = *(const float4*)in;
    ushort4 o;
    o.x = f2bf(v.x); o.y = f2bf(v.y); o.z = f2bf(v.z); o.w = f2bf(v.w);
    *(ushort4*)out = o;
}

// ---------------- fused weight transposes fp32[R,C] -> bf16[C,R], z-indexed ----------------
__global__ void transpose_weights(const float* __restrict__ Wq, const float* __restrict__ Wk,
                                  const float* __restrict__ Wv, const float* __restrict__ Wo,
                                  unsigned short* __restrict__ WqT, unsigned short* __restrict__ WkvT,
                                  unsigned short* __restrict__ WoT) {
    __shared__ float t[32][33];
    const float* in;
    unsigned short* out;
    int R;
    const int C = 2048;
    switch (blockIdx.z) {
        case 0:  in = Wq; out = WqT;                R = 2048; break;
        case 1:  in = Wk; out = WkvT;               R = 1024; break;
        case 2:  in = Wv; out = WkvT + 2048 * 1024; R = 1024; break;
        default: in = Wo; out = WoT;                R = 2048; break;
    }
    int r0 = blockIdx.y * 32, c0 = blockIdx.x * 32;
    if (r0 >= R) return;
    int tx = threadIdx.x, ty = threadIdx.y;            // block (32,8)
    #pragma unroll
    for (int i = 0; i < 32; i += 8) t[ty + i][tx] = in[(long)(r0 + ty + i) * C + c0 + tx];
    __syncthreads();
    #pragma unroll
    for (int i = 0; i < 32; i += 8) out[(long)(c0 + ty + i) * R + r0 + tx] = f2bf(t[tx][ty + i]);
}

// ---------------- combine Q split-K=4 partials + bias + RoPE -> Q_bf head layout ----------------
__global__ void combine_q_rope(const float* __restrict__ P, const float* __restrict__ bq,
                               unsigned short* __restrict__ Q) {
    int gid = blockIdx.x * 256 + threadIdx.x;          // 1,048,576 pairs
    int p = gid & 63;
    int h = (gid >> 6) & 15;
    int m = gid >> 10;                                 // 0..1023
    int n = h * 128 + 2 * p;
    long i0 = (long)m * 2048 + n;
    float q1 = bq[n], q2 = bq[n + 1];
    #pragma unroll
    for (int pt = 0; pt < 4; pt++) {
        float2 a = *(const float2*)(P + (long)pt * 2097152 + i0);
        q1 += a.x; q2 += a.y;
    }
    int l = m & 255, b = m >> 8;
    float inv = powf(10000.0f, -(float)p * (1.0f / 64.0f));
    float s, c;
    sincosf((float)l * inv, &s, &c);
    const float sc = 0.08838834764831845f;             // 1/sqrt(128)
    long qi = (((long)(b * 16 + h) * 256 + l) << 7) + 2 * p;
    ushort2 o;
    o.x = f2bf((q1 * c - q2 * s) * sc);
    o.y = f2bf((q1 * s + q2 * c) * sc);
    *(ushort2*)(Q + qi) = o;
}

// ---------------- combine O split-K=4 partials + bias -> fp32 out ----------------
__global__ void combine_o(const float* __restrict__ P, const float* __restrict__ bo,
                          float* __restrict__ out) {
    int gid = blockIdx.x * 256 + threadIdx.x;          // 524288
    long e = (long)gid * 4;
    int n = (int)(e & 2047);
    float4 r = *(const float4*)(bo + n);
    #pragma unroll
    for (int pt = 0; pt < 4; pt++) {
        float4 a = *(const float4*)(P + (long)pt * 2097152 + e);
        r.x += a.x; r.y += a.y; r.z += a.z; r.w += a.w;
    }
    *(float4*)(out + e) = r;
}

// ================= fused flash attention =================
// grid (4 l-tiles, 64 bh), 256 threads. Q-tile [64x128] in regs (scale folded),
// loop 16 K/V m-tiles of 128: S=QK^T (fp32 frags), online softmax (C-layout:
// row=quad*4+r, col=l16; shfl_xor over l16 + LDS cross-wave), P -> LDS bf16
// (C->A layout bounce), O += P@V from LDS (Vt rows = d, B^T form).
// Out: ctx[b*256+l][h*128+d] bf16.
__launch_bounds__(256)
__global__ void flash_attn(const unsigned short* __restrict__ Q,
                           const unsigned short* __restrict__ Kb,
                           const unsigned short* __restrict__ Vtg,
                           unsigned short* __restrict__ ctx) {
    __shared__ __align__(16) unsigned short Ks[16384];   // [128 m][128 d]
    __shared__ __align__(16) unsigned short Vs[16384];   // [128 d][128 m]
    __shared__ __align__(16) unsigned short Ps[64 * 136];
    __shared__ float m_state[64], l_state[64], nmw[64], alw[64];
    __shared__ float pmax[64][2], psum[64][2];

    const int bh = blockIdx.y, l0 = blockIdx.x * 64;
    const int b = bh >> 4, h = bh & 15;
    const int tid = threadIdx.x, w = tid >> 6, lane = tid & 63;
    const int quad = lane >> 4, l16 = lane & 15;
    const int wr = w >> 1, wc = w & 1;

    const unsigned short* Qb = Q   + (((long)bh * 256 + l0) << 7);
    const unsigned short* Kt = Kb  + ((long)bh << 18);   // bh*2048*128
    const unsigned short* Vb = Vtg + ((long)bh << 18);   // bh*128*2048

    // Q fragments (A-operand), kept in registers for all 16 iterations
    bf16x8 af[2][4];
    #pragma unroll
    for (int i = 0; i < 2; i++)
        #pragma unroll
        for (int kk = 0; kk < 4; kk++)
            af[i][kk] = *(const bf16x8*)(Qb + (long)(wr * 32 + i * 16 + l16) * 128 + kk * 32 + quad * 8);

    f32x4 o[2][4] = {};
    if (tid < 64) { m_state[tid] = -1e30f; l_state[tid] = 0.f; }
    __syncthreads();

    for (int t = 0; t < 16; t++) {
        // ---- stage K-tile (flat 32KB copy) and V-tile (Vt rows, stride 2048) ----
        const unsigned short* Kg = Kt + (long)t * 16384;
        #pragma unroll
        for (int q = 0; q < 8; q++) {
            int c = w * 8 + q;
            load_lds16(Kg + c * 512 + lane * 8, (void*)(Ks + c * 512));
        }
        #pragma unroll
        for (int q = 0; q < 8; q++) {
            int c = w * 8 + q;
            int rd = c * 4 + (lane >> 4);
            load_lds16(Vb + (long)rd * 2048 + t * 128 + (lane & 15) * 8, (void*)(Vs + c * 512));
        }
        __syncthreads();                 // staging complete (vmcnt drained)

        // ---- S = Q @ K^T ----
        f32x4 s[2][4] = {};
        #pragma unroll
        for (int kk = 0; kk < 4; kk++) {
            bf16x8 bk[4];
            #pragma unroll
            for (int j = 0; j < 4; j++)
                bk[j] = *(const bf16x8*)(Ks + (wc * 64 + j * 16 + l16) * 128 + kk * 32 + quad * 8);
            #pragma unroll
            for (int i = 0; i < 2; i++)
                #pragma unroll
                for (int j = 0; j < 4; j++)
                    s[i][j] = __builtin_amdgcn_mfma_f32_16x16x32_bf16(af[i][kk], bk[j], s[i][j], 0, 0, 0);
        }

        // ---- row max (over this tile's 128 cols) ----
        #pragma unroll
        for (int i = 0; i < 2; i++)
            #pragma unroll
            for (int r = 0; r < 4; r++) {
                float mx = fmaxf(fmaxf(s[0 + i][0][r], s[i][1][r]), fmaxf(s[i][2][r], s[i][3][r]));
                #pragma unroll
                for (int off = 1; off < 16; off <<= 1) mx = fmaxf(mx, __shfl_xor(mx, off));
                if (l16 == 0) pmax[wr * 32 + i * 16 + quad * 4 + r][wc] = mx;
            }
        __syncthreads();
        if (tid < 64) {
            float nm = fmaxf(m_state[tid], fmaxf(pmax[tid][0], pmax[tid][1]));
            alw[tid] = __expf(m_state[tid] - nm);
            nmw[tid] = nm;
            m_state[tid] = nm;
        }
        __syncthreads();

        // ---- P = exp(S - nm), row sum, rescale O, write P -> Ps (bf16) ----
        #pragma unroll
        for (int i = 0; i < 2; i++)
            #pragma unroll
            for (int r = 0; r < 4; r++) {
                int row = wr * 32 + i * 16 + quad * 4 + r;
                float nm = nmw[row];
                float al = alw[row];
                float ls = 0.f;
                #pragma unroll
                for (int j = 0; j < 4; j++) {
                    float p = __expf(s[i][j][r] - nm);
                    s[i][j][r] = p;
                    ls += p;
                    o[i][j][r] *= al;
                    Ps[row * 136 + wc * 64 + j * 16 + l16] = f2bf(p);
                }
                #pragma unroll
                for (int off = 1; off < 16; off <<= 1) ls += __shfl_xor(ls, off);
                if (l16 == 0) psum[row][wc] = ls;
            }
        __syncthreads();
        if (tid < 64) l_state[tid] = l_state[tid] * alw[tid] + psum[tid][0] + psum[tid][1];

        // ---- O += P @ V ----
        #pragma unroll
        for (int kk = 0; kk < 4; kk++) {
            bf16x8 pa[2], vb[4];
            #pragma unroll
            for (int i = 0; i < 2; i++)
                pa[i] = *(const bf16x8*)(Ps + (wr * 32 + i * 16 + l16) * 136 + kk * 32 + quad * 8);
            #pragma unroll
            for (int j = 0; j < 4; j++)
                vb[j] = *(const bf16x8*)(Vs + (wc * 64 + j * 16 + l16) * 128 + kk * 32 + quad * 8);
            #pragma unroll
            for (int i = 0; i < 2; i++)
                #pragma unroll
                for (int j = 0; j < 4; j++)
                    o[i][j] = __builtin_amdgcn_mfma_f32_16x16x32_bf16(pa[i], vb[j], o[i][j], 0, 0, 0);
        }
        __syncthreads();                 // Ks/Vs/Ps reused next iteration
    }

    // ---- epilogue: normalize, bounce through Ps, 16B stores ----
    #pragma unroll
    for (int i = 0; i < 2; i++)
        #pragma unroll
        for (int r = 0; r < 4; r++) {
            int row = wr * 32 + i * 16 + quad * 4 + r;
            float rinv = 1.0f / l_state[row];
            #pragma unroll
            for (int j = 0; j < 4; j++)
                Ps[row * 136 + wc * 64 + j * 16 + l16] = f2bf(o[i][j][r] * rinv);
        }
    __syncthreads();
    #pragma unroll
    for (int pass = 0; pass < 4; pass++) {
        int sid = pass * 256 + tid;
        int row = sid >> 4, seg = sid & 15;
        bf16x8 val = *(const bf16x8*)(Ps + row * 136 + seg * 8);
        *(bf16x8*)(ctx + ((long)(b * 256 + l0 + row)) * 2048 + h * 128 + seg * 8) = val;
    }
}

// ---------------- bf16 GEMM (128x128, 256 thr): C = A[M,K] * Bt[N,K]^T ----------------
// EPI 1: KV fused. n0 < nsplit: K half -> outA[b*16+h][le][128] + biasA.
//        n0 >= nsplit: V half -> outB (Vt) [b*16+h][d][2048] + biasB, transposed bounce.
// EPI 4: fp32 split-K partial; z -> s=z/zdiv, bh=z%zdiv; out[(s*zdiv+bh)][M][N]
template <int EPI>
__launch_bounds__(256)
__global__ void gemm_bt(const unsigned short* __restrict__ A, const unsigned short* __restrict__ Bt,
                        const float* __restrict__ biasA, const float* __restrict__ biasB,
                        void* __restrict__ outA, void* __restrict__ outB,
                        int M, int N, int K, int lda, int ldb,
                        long strideA, long strideB, int zdiv, int nsplit) {
    __shared__ __align__(16) unsigned short smem[16384];  // 32 KB: 2 stages
    const int z = blockIdx.z;
    int s = 0, bh = z;
    if constexpr (EPI == 4) { s = z / zdiv; bh = z - s * zdiv; }
    const unsigned short* Ab = A + (long)bh * strideA + (long)s * K;
    const unsigned short* Bb = Bt + (long)bh * strideB + (long)s * K;
    const int m0 = blockIdx.y * 128, n0 = blockIdx.x * 128;
    const int tid = threadIdx.x;
    const int w = tid >> 6, lane = tid & 63;
    const int quad = lane >> 4, l16 = lane & 15;
    const int wr = w >> 1, wc = w & 1;
    const int srow = lane >> 2;
    const int scol = (lane & 3) * 8;

    f32x4 acc[4][4] = {};

    auto stage = [&](int k0, int p) {
        unsigned short* As = smem + p * 8192;
        unsigned short* Bs = As + 4096;
        #pragma unroll
        for (int q = 0; q < 2; q++) {
            int ci = q * 4 + w;
            int row = ci * 16 + srow;
            load_lds16(Ab + (long)(m0 + row) * lda + k0 + scol, (void*)(As + ci * 512));
            load_lds16(Bb + (long)(n0 + row) * ldb + k0 + scol, (void*)(Bs + ci * 512));
        }
    };

    const int nk = K >> 5;
    stage(0, 0);
    for (int i = 0; i < nk; i++) {
        __syncthreads();
        if (i + 1 < nk) stage((i + 1) << 5, (i + 1) & 1);
        const unsigned short* As = smem + (i & 1) * 8192;
        const unsigned short* Bs = As + 4096;
        bf16x8 af[4], bfr[4];
        #pragma unroll
        for (int ii = 0; ii < 4; ii++) {
            int r = wr * 64 + ii * 16 + l16;
            af[ii] = *(const bf16x8*)(As + r * 32 + quad * 8);
        }
        #pragma unroll
        for (int j = 0; j < 4; j++) {
            int r = wc * 64 + j * 16 + l16;
            bfr[j] = *(const bf16x8*)(Bs + r * 32 + quad * 8);
        }
        #pragma unroll
        for (int ii = 0; ii < 4; ii++)
            #pragma unroll
            for (int j = 0; j < 4; j++)
                acc[ii][j] = __builtin_amdgcn_mfma_f32_16x16x32_bf16(af[ii], bfr[j], acc[ii][j], 0, 0, 0);
    }
    __syncthreads();

    if constexpr (EPI == 1) {
        const int b = m0 >> 11;                        // m = b*2048 + le
        const int le0 = m0 & 2047;
        if (n0 < nsplit) {
            const int h = n0 >> 7;
            unsigned short* dst = (unsigned short*)outA + ((((long)(b * 16 + h)) << 11) << 7);
            #pragma unroll
            for (int pp = 0; pp < 2; pp++) {
                if (wr == pp) {
                    #pragma unroll
                    for (int i = 0; i < 4; i++)
                        #pragma unroll
                        for (int j = 0; j < 4; j++)
                            #pragma unroll
                            for (int r = 0; r < 4; r++) {
                                int ml = i * 16 + quad * 4 + r;
                                int n  = wc * 64 + j * 16 + l16;
                                smem[ml * 136 + n] = f2bf(acc[i][j][r] + biasA[n0 + n]);
                            }
                }
                __syncthreads();
                #pragma unroll
                for (int pass = 0; pass < 4; pass++) {
                    int row = pass * 16 + (tid >> 4);
                    int seg = tid & 15;
                    bf16x8 val = *(const bf16x8*)(smem + row * 136 + seg * 8);
                    long le = le0 + pp * 64 + row;
                    *(bf16x8*)(dst + (le << 7) + seg * 8) = val;
                }
                __syncthreads();
            }
        } else {
            const int n0e = n0 - nsplit;
            const int h = n0e >> 7;
            unsigned short* vbase = (unsigned short*)outB + ((long)(b * 16 + h)) * (128 * 2048);
            #pragma unroll
            for (int pp = 0; pp < 2; pp++) {
                if (wr == pp) {
                    #pragma unroll
                    for (int i = 0; i < 4; i++)
                        #pragma unroll
                        for (int j = 0; j < 4; j++) {
                            int d = wc * 64 + j * 16 + l16;
                            float bvd = biasB[n0e + d];
                            #pragma unroll
                            for (int r = 0; r < 4; r++) {
                                int ml = i * 16 + quad * 4 + r;
                                smem[d * 72 + ml] = f2bf(acc[i][j][r] + bvd);
                            }
                        }
                }
                __syncthreads();
                #pragma unroll
                for (int pass = 0; pass < 4; pass++) {
                    int d = pass * 32 + (tid >> 3);
                    int c = tid & 7;
                    bf16x8 val = *(const bf16x8*)(smem + d * 72 + c * 8);
                    *(bf16x8*)(vbase + (long)d * 2048 + le0 + pp * 64 + c * 8) = val;
                }
                __syncthreads();
            }
        }
    } else {
        float* smf = (float*)smem;
        long zo = ((long)s * zdiv + bh) * (long)M * N;
        #pragma unroll
        for (int q4 = 0; q4 < 4; q4++) {
            if (wr == (q4 >> 1)) {
                #pragma unroll
                for (int ii = 0; ii < 2; ii++) {
                    int i = (q4 & 1) * 2 + ii;
                    #pragma unroll
                    for (int j = 0; j < 4; j++)
                        #pragma unroll
                        for (int r = 0; r < 4; r++) {
                            int ml = ii * 16 + quad * 4 + r;
                            int n  = wc * 64 + j * 16 + l16;
                            smf[ml * 132 + n] = acc[i][j][r];
                        }
                }
            }
            __syncthreads();
            #pragma unroll
            for (int pass = 0; pass < 4; pass++) {
                int row = pass * 8 + (tid >> 5);
                int seg = tid & 31;
                float4 val = *(const float4*)(smf + row * 132 + seg * 4);
                int m = m0 + q4 * 32 + row;
                *(float4*)((float*)outA + zo + (long)m * N + n0 + seg * 4) = val;
            }
            __syncthreads();
        }
    }
}

extern "C" void kernel_launch(void* const* d_in, const int* in_sizes, int n_in,
                              void* d_out, int out_size, void* d_ws, size_t ws_size,
                              hipStream_t stream) {
    const float* x   = (const float*)d_in[0];
    const float* enc = (const float*)d_in[1];
    const float* Wq  = (const float*)d_in[2];
    const float* bq  = (const float*)d_in[3];
    const float* Wk  = (const float*)d_in[4];
    const float* bk  = (const float*)d_in[5];
    const float* Wv  = (const float*)d_in[6];
    const float* bv  = (const float*)d_in[7];
    const float* Wo  = (const float*)d_in[8];
    const float* bo  = (const float*)d_in[9];
    float* out = (float*)d_out;

    // ws layout (MB offsets), liveness overlays:
    //   0: x_bf(4) | 4: enc_bf(16) | 20: WqT(8) | 28: WkvT(8) | 68: K_bf(32)
    // 100: WoT(8) | 108: Q_bf(4) | 112: Vt(64)
    //  Pq(32)@36    [dead after combine_q]
    //  ctx_bf(4)@0  [x_bf dead after Q-GEMM; flash reads Q_bf@108 — no overlap]
    //  Po(32)@8     [enc_bf/WqT/WkvT dead after KV-GEMM; clear of ctx_bf@0-4 and WoT@100]
    char* ws = (char*)d_ws;
    const size_t MB = 1024 * 1024;
    unsigned short* x_bf   = (unsigned short*)(ws + 0 * MB);
    unsigned short* enc_bf = (unsigned short*)(ws + 4 * MB);
    unsigned short* WqT    = (unsigned short*)(ws + 20 * MB);
    unsigned short* WkvT   = (unsigned short*)(ws + 28 * MB);
    unsigned short* K_bf   = (unsigned short*)(ws + 68 * MB);
    unsigned short* WoT    = (unsigned short*)(ws + 100 * MB);
    unsigned short* Q_bf   = (unsigned short*)(ws + 108 * MB);
    unsigned short* Vt     = (unsigned short*)(ws + 112 * MB);
    float*          Pq     = (float*)(ws + 36 * MB);
    unsigned short* ctx_bf = (unsigned short*)(ws + 0 * MB);
    float*          Po     = (float*)(ws + 8 * MB);

    // fused casts (x + enc)
    cast_all<<<10240, 256, 0, stream>>>(x, enc, x_bf, enc_bf);

    // fused weight transposes
    transpose_weights<<<dim3(64, 64, 4), dim3(32, 8), 0, stream>>>(Wq, Wk, Wv, Wo, WqT, WkvT, WoT);

    // Q partials = x @ Wq, split-K=4 (K=512 each) -> Pq[4][1024][2048]
    gemm_bt<4><<<dim3(16, 8, 4), 256, 0, stream>>>(x_bf, WqT, nullptr, nullptr, Pq, nullptr,
                                                   1024, 2048, 512, 2048, 2048, 0, 0, 1, 0);
    combine_q_rope<<<4096, 256, 0, stream>>>(Pq, bq, Q_bf);

    // K|V = enc @ [Wk|Wv] + bias -> K_bf head layout; V -> Vt transposed (epilogue)
    gemm_bt<1><<<dim3(32, 64, 1), 256, 0, stream>>>(enc_bf, WkvT, bk, bv, K_bf, Vt,
                                                    8192, 4096, 1024, 1024, 1024, 0, 0, 1, 2048);

    // fused attention: softmax(Q K^T) V -> ctx_bf [b*256+l][h*128+d]
    flash_attn<<<dim3(4, 64), 256, 0, stream>>>(Q_bf, K_bf, Vt, ctx_bf);

    // O partials = ctx @ Wo, split-K=4 (K=512 each) -> Po[4][1024][2048]
    gemm_bt<4><<<dim3(16, 8, 4), 256, 0, stream>>>(ctx_bf, WoT, nullptr, nullptr, Po, nullptr,
                                                   1024, 2048, 512, 2048, 2048, 0, 0, 1, 0);
    combine_o<<<2048, 256, 0, stream>>>(Po, bo, out);
}